// Round 11
// baseline (420.728 us; speedup 1.0000x reference)
//
#include <hip/hip_runtime.h>
#include <hip/hip_cooperative_groups.h>
#include <hip/hip_bf16.h>
#include <math.h>

namespace cg = cooperative_groups;

// Problem constants (T=64, B=256, N=512)
#define TT 64
#define BB 256
#define NN 512

typedef __attribute__((ext_vector_type(8)))  short s16x8;   // 8 bf16 = 4 VGPR
typedef __attribute__((ext_vector_type(16))) float f32x16;  // 32x32 C/D frag

// global -> LDS direct DMA, 16B per lane (lds dest wave-uniform, src per-lane)
__device__ __forceinline__ void gload16(const void* g, void* l) {
  __builtin_amdgcn_global_load_lds(
      (const __attribute__((address_space(1))) unsigned int*)g,
      (__attribute__((address_space(3))) unsigned int*)l, 16, 0, 0);
}

__device__ __forceinline__ unsigned bf16_rne(float v) {
  unsigned u = __float_as_uint(v);
  return (u + 0x7FFFu + ((u >> 16) & 1u)) >> 16;
}

// ---------------------------------------------------------------------------
// Chunk layout (bf16): 1KB chunk = 32 rows x 16 k, MFMA 32x32x16 frag order:
// ushort idx within chunk = ((k>>3)&1)*256 + (row&31)*8 + (k&7).
// A (spikes): chunk id = rg*32 + kc (rg=row>>5 0..511, kc=k>>4 0..31).
// W: 3 comp planes of 512 chunks, chunk id = cg*32 + kc (cg=m>>5 0..15).
// gload16 of a chunk = base + l*16 -> lane-contiguous, perfectly coalesced.
// ---------------------------------------------------------------------------
__global__ __launch_bounds__(512) void mega_kernel(
    const float* __restrict__ x, const float* __restrict__ W,
    const float* __restrict__ gamma, const float* __restrict__ beta,
    float* __restrict__ out, unsigned short* __restrict__ WT,
    unsigned short* __restrict__ spkT, float* __restrict__ pS,
    float* __restrict__ pQ, float* __restrict__ mu, float* __restrict__ inv) {
  extern __shared__ char smem[];        // 131072 B, re-used per phase
  __shared__ float rms[TT];
  __shared__ float sp[TT];
  cg::grid_group grid = cg::this_grid();
  int tid = threadIdx.x;
  int l = tid & 63, w = tid >> 6;       // 8 waves
  int blk = blockIdx.x;                 // 256 blocks

  // ===== phase 0: wprep — W -> 3 RNE-bf16 components (2 elems/thread) =====
  #pragma unroll
  for (int r = 0; r < 2; ++r) {
    int i = blk * 512 + tid + r * 131072;   // i = m*512 + k
    int m = i >> 9, k = i & 511;
    float v = W[i];
    unsigned h0 = bf16_rne(v);
    float f0 = __uint_as_float(h0 << 16);
    float r1 = v - f0;
    unsigned h1 = bf16_rne(r1);
    float f1 = __uint_as_float(h1 << 16);
    float r2 = r1 - f1;
    unsigned h2 = bf16_rne(r2);             // w0+w1+w2, residual <= 2^-27|W|
    int cgp = m >> 5, kc = k >> 4;
    size_t base = ((size_t)cgp * 32 + kc) * 512
                + ((m & 31) + 32 * ((k >> 3) & 1)) * 8 + (k & 7);
    WT[base         ] = (unsigned short)h0;
    WT[base + 262144] = (unsigned short)h1;
    WT[base + 524288] = (unsigned short)h2;
  }

  // ===== phase 1: frontend for b = blk (proven absmax 0.0) =====
  {
    float* xs = (float*)smem;           // [64][512]
    int b = blk;
    #pragma unroll
    for (int p = 0; p < 16; ++p) {
      int f = p * 512 + tid;
      int t = f >> 7, c4 = f & 127;
      gload16(x + (size_t)t * (BB * NN) + (size_t)b * NN + c4 * 4,
              (char*)xs + p * 8192 + w * 1024);
    }
    __syncthreads();                    // drains vmcnt(0)
    #pragma unroll
    for (int j = 0; j < 8; ++j) {       // wave w owns rows w*8..w*8+7
      int t = w * 8 + j;
      float s = 0.f;
      #pragma unroll
      for (int q = 0; q < 8; ++q) s += xs[t * 512 + q * 64 + l];
      #pragma unroll
      for (int off = 32; off; off >>= 1) s += __shfl_xor(s, off);
      if (l == 0) rms[t] = s;
    }
    float cs = 0.f;
    for (int t = 0; t < TT; ++t) cs += xs[t * 512 + tid];
    __syncthreads();
    if (w == 0) {                       // spatial LIF scan, reg/shfl chain
      float myrm = rms[l];
      float v = 0.f;
      unsigned long long mask = 0ull;
      #pragma unroll
      for (int t = 0; t < TT; ++t) {
        float m = __shfl(myrm, t) * (1.0f / 512.0f);
        v = v * 0.5f + m;               // == v - v/2 + m exactly
        if (v >= 1.0f) { mask |= (1ull << t); v = 0.f; }
      }
      sp[l] = (float)((mask >> l) & 1ull);
    }
    __syncthreads();
    float te = (cs * (1.0f / 64.0f) >= 1.0f) ? 1.0f : 0.0f;
    float v = 0.f;
    unsigned short* sb = spkT + (size_t)(b >> 5) * 16384 + (tid >> 4) * 512
                       + (b & 31) * 8 + ((tid >> 3) & 1) * 256 + (tid & 7);
    for (int t = 0; t < TT; ++t) {
      float xv = xs[t * 512 + tid];
      float a = xv + (xv * sp[t]) * (xv * te);  // ==xv when a gate is 0
      v = v * 0.5f + a;
      unsigned short s = (v >= 1.0f) ? 0x3F80 : 0;
      sb[(size_t)t * 131072] = s;
      if (s) v = 0.f;
    }
  }
  __threadfence();
  grid.sync();

  // ===== phase 2: GEMM — tile 128x256, 8 waves (2x4), BK=32, 2x56KB dbuf ====
  {
    unsigned char* sm0 = (unsigned char*)smem;
    int nt = blk & 1, bx = blk >> 1;    // col-half, row-tile
    int wr = w >> 2, wc = w & 3;        // wave = 64x64 out
    int lr = l & 31, lh = l >> 5;

    f32x16 acc[2][2];
    #pragma unroll
    for (int f = 0; f < 2; ++f)
      #pragma unroll
      for (int g = 0; g < 2; ++g)
        #pragma unroll
        for (int j = 0; j < 16; ++j) acc[f][g][j] = 0.f;

    // 56 chunks/K-tile: A cc=0..7 at cc*1024; B bb=0..47 at 8192+bb*1024,
    // bb = (comp*8 + cg)*2 + kc2. 7 gload16 per wave (balanced).
    auto STAGE = [&](unsigned char* lbase, int kt) {
      #pragma unroll
      for (int j = 0; j < 7; ++j) {
        int cc = j * 8 + w;
        if (cc < 8) {
          int rg = bx * 4 + (cc >> 1), kc = kt * 2 + (cc & 1);
          gload16((const char*)spkT + ((size_t)rg * 32 + kc) * 1024 + l * 16,
                  lbase + cc * 1024);
        } else {
          int bb = cc - 8;
          int comp = bb >> 4, cgl = (bb >> 1) & 7, kc2 = bb & 1;
          gload16((const char*)WT + (size_t)comp * 524288
                    + (((size_t)(nt * 8 + cgl) * 32) + kt * 2 + kc2) * 1024 + l * 16,
                  lbase + 8192 + bb * 1024);
        }
      }
    };

    STAGE(sm0, 0);
    for (int kt = 0; kt < 16; ++kt) {
      asm volatile("s_waitcnt lgkmcnt(0)" ::: "memory");  // prev-buf reads done
      asm volatile("s_waitcnt vmcnt(0)" ::: "memory");    // my stage landed
      __builtin_amdgcn_s_barrier();
      if (kt < 15) STAGE(sm0 + ((kt + 1) & 1) * 57344, kt + 1);
      const unsigned char* bp = sm0 + (kt & 1) * 57344;
      #pragma unroll
      for (int kc2 = 0; kc2 < 2; ++kc2) {
        s16x8 a[2], bf[2][3];
        #pragma unroll
        for (int f = 0; f < 2; ++f)
          a[f] = *(const s16x8*)(bp + ((wr * 2 + f) * 2 + kc2) * 1024 + l * 16);
        #pragma unroll
        for (int g = 0; g < 2; ++g)
          #pragma unroll
          for (int c = 0; c < 3; ++c)
            bf[g][c] = *(const s16x8*)(bp + 8192 + ((size_t)((c * 8 + wc * 2 + g) * 2 + kc2)) * 1024 + l * 16);
        __builtin_amdgcn_s_setprio(1);
        #pragma unroll
        for (int c = 0; c < 3; ++c)
          #pragma unroll
          for (int f = 0; f < 2; ++f)
            #pragma unroll
            for (int g = 0; g < 2; ++g)
              acc[f][g] = __builtin_amdgcn_mfma_f32_32x32x16_bf16(a[f], bf[g][c], acc[f][g], 0, 0, 0);
        __builtin_amdgcn_s_setprio(0);
      }
    }

    // epilogue: C write + BN partials (lh=0/1 combine across lane^32)
    #pragma unroll
    for (int g = 0; g < 2; ++g) {
      int col = nt * 256 + wc * 64 + g * 32 + lr;
      float sy = 0.f, sq = 0.f;
      #pragma unroll
      for (int f = 0; f < 2; ++f)
        #pragma unroll
        for (int j = 0; j < 16; ++j) {
          float y = acc[f][g][j];
          int row = bx * 128 + wr * 64 + f * 32 + (j & 3) + 8 * (j >> 2) + 4 * lh;
          out[(size_t)row * NN + col] = y;
          sy += y; sq += y * y;
        }
      sy += __shfl_xor(sy, 32);
      sq += __shfl_xor(sq, 32);
      if (lh == 0) {
        pS[(size_t)col * 256 + bx * 2 + wr] = sy;
        pQ[(size_t)col * 256 + bx * 2 + wr] = sq;
      }
    }
  }
  __threadfence();
  grid.sync();

  // ===== phase 3: BN stats reduce (2 channels/block, waves 0-1) =====
  if (tid < 128) {
    int ch = blk * 2 + (tid >> 6), ll = tid & 63;
    const float* ps = pS + (size_t)ch * 256;
    const float* pq = pQ + (size_t)ch * 256;
    float s = (ps[ll] + ps[ll + 64]) + (ps[ll + 128] + ps[ll + 192]);
    float q = (pq[ll] + pq[ll + 64]) + (pq[ll + 128] + pq[ll + 192]);
    #pragma unroll
    for (int off = 32; off; off >>= 1) { s += __shfl_xor(s, off); q += __shfl_xor(q, off); }
    if (ll == 0) {
      float mean = s * (1.0f / 16384.0f);
      float var  = q * (1.0f / 16384.0f) - mean * mean;
      mu[ch] = mean;
      inv[ch] = 1.0f / sqrtf(var + 1e-5f);
    }
  }
  __threadfence();
  grid.sync();

  // ===== phase 4: BN normalize + final LIF, 16-deep prefetch, in-place =====
  {
    int g = blk * 512 + tid;            // (b, m), 131072 threads
    int b = g >> 9, m = g & 511;
    float MU = mu[m], IV = inv[m], G = gamma[m], BE = beta[m];
    float* p = out + (size_t)b * NN + m;
    const size_t st = (size_t)BB * NN;
    float buf[16], nxt[16];
    #pragma unroll
    for (int j = 0; j < 16; ++j) buf[j] = p[(size_t)j * st];
    float v = 0.f;
    #pragma unroll
    for (int t0 = 0; t0 < 64; t0 += 16) {
      if (t0 + 16 < 64) {
        #pragma unroll
        for (int j = 0; j < 16; ++j) nxt[j] = p[(size_t)(t0 + 16 + j) * st];
      }
      #pragma unroll
      for (int j = 0; j < 16; ++j) {
        float xb = (buf[j] - MU) * IV * G + BE;
        v = v * 0.5f + xb;
        float s = (v >= 1.0f) ? 1.0f : 0.0f;
        p[(size_t)(t0 + j) * st] = s;
        if (s != 0.f) v = 0.f;
      }
      #pragma unroll
      for (int j = 0; j < 16; ++j) buf[j] = nxt[j];
    }
  }
}

// ---------------------------------------------------------------------------
extern "C" void kernel_launch(void* const* d_in, const int* in_sizes, int n_in,
                              void* d_out, int out_size, void* d_ws, size_t ws_size,
                              hipStream_t stream) {
  const float* x     = (const float*)d_in[0];   // [T,B,N]
  const float* W     = (const float*)d_in[1];   // [N,N]
  const float* gamma = (const float*)d_in[2];   // [N]
  const float* beta  = (const float*)d_in[3];   // [N]
  float* out = (float*)d_out;                   // [T,B,N] fp32

  // workspace layout (~19.4 MB)
  char* ws = (char*)d_ws;
  unsigned short* WT   = (unsigned short*)ws;               //  1,572,864
  unsigned short* spkT = (unsigned short*)(ws + 1572864);   // 16,777,216
  float* pS    = (float*)(ws + 18350080);                   //    524,288
  float* pQ    = (float*)(ws + 18874368);                   //    524,288
  float* bn_mu = (float*)(ws + 19398656);                   //      2,048
  float* bn_inv= (float*)(ws + 19400704);                   //      2,048

  void* args[] = {(void*)&x, (void*)&W, (void*)&gamma, (void*)&beta,
                  (void*)&out, (void*)&WT, (void*)&spkT, (void*)&pS,
                  (void*)&pQ, (void*)&bn_mu, (void*)&bn_inv};
  hipLaunchCooperativeKernel((void*)mega_kernel, dim3(256), dim3(512),
                             args, 131072, stream);
}